// Round 4
// baseline (215.487 us; speedup 1.0000x reference)
//
#include <hip/hip_runtime.h>
#include <hip/hip_bf16.h>
#include <cstdint>

typedef __attribute__((ext_vector_type(8))) _Float16 half8;
typedef __attribute__((ext_vector_type(2))) float f32x2;
typedef __attribute__((ext_vector_type(4))) float f32x4;

#define N_NODES 20000
#define N_EDGES 320000
#define IN_DIM 512
#define HID 256
#define N_GRAPHS 256
#define NPB 8            // nodes per aggregate block (4 wave-groups x 2 nodes)
#define ECH 1024         // edge-staging chunk (int2 -> 8 KB LDS)

// ---- prep: W transpose->f16  +  in-degree hist over dst  +  batch hist ----
#define PREP_W   (IN_DIM * HID)            // 131072
#define PREP_E   (PREP_W + N_EDGES)        // 451072
#define PREP_B   (PREP_E + N_NODES)        // 471072
__global__ __launch_bounds__(256) void prep_kernel(const float* __restrict__ W,
                                                   const int* __restrict__ dst,
                                                   const int* __restrict__ batch,
                                                   _Float16* __restrict__ wt,
                                                   int* __restrict__ ecnt,
                                                   int* __restrict__ counts) {
    int t = blockIdx.x * 256 + threadIdx.x;
    if (t < PREP_W) {
        wt[t] = (_Float16)W[(t & 511) * HID + (t >> 9)];   // wt[n*512+k] = W[k*256+n]
    } else if (t < PREP_E) {
        atomicAdd(&ecnt[dst[t - PREP_W]], 1);
    } else if (t < PREP_B) {
        atomicAdd(&counts[batch[t - PREP_E]], 1);
    }
}

// ---- single-block scan of ecnt -> offsets[0..N], fused dinv; shfl wave-scans ----
__global__ __launch_bounds__(1024) void scan_dinv_kernel(const int* __restrict__ ecnt,
                                                         int* __restrict__ offsets,
                                                         float* __restrict__ dinv) {
    __shared__ int wsum[16];
    int t = threadIdx.x;
    int lane = t & 63, wid = t >> 6;
    const int CHS = 20;                    // 1024*20 >= 20000; t<1000 fully in-range
    int base = t * CHS;
    int vals[CHS];
    int s = 0;
    if (t < 1000) {
        const int4* p = reinterpret_cast<const int4*>(ecnt + base);
#pragma unroll
        for (int i = 0; i < 5; ++i) {
            int4 v = p[i];
            vals[4*i+0] = v.x; vals[4*i+1] = v.y; vals[4*i+2] = v.z; vals[4*i+3] = v.w;
        }
#pragma unroll
        for (int i = 0; i < CHS; ++i) s += vals[i];
    }
    int incl = s;
#pragma unroll
    for (int off = 1; off < 64; off <<= 1) {
        int u = __shfl_up(incl, off, 64);
        if (lane >= off) incl += u;
    }
    if (lane == 63) wsum[wid] = incl;
    __syncthreads();
    if (t < 16) {
        int v = wsum[t];
#pragma unroll
        for (int off = 1; off < 16; off <<= 1) {
            int u = __shfl_up(v, off, 16);
            if (t >= off) v += u;
        }
        wsum[t] = v;
    }
    __syncthreads();
    int woff = (wid == 0) ? 0 : wsum[wid - 1];
    if (t < 1000) {
        int run = woff + incl - s;
#pragma unroll
        for (int i = 0; i < CHS; ++i) {
            int idx = base + i;
            offsets[idx] = run;
            dinv[idx] = rsqrtf((float)(vals[i] + 1));
            run += vals[i];
        }
    }
    if (t == 1023) offsets[N_NODES] = wsum[15];
}

// ---- fused: gemm (blocks [0,GEMM_BLOCKS)) + csr scatter (rest) ----
// independent work, different pipes (MFMA vs latency) -> co-scheduled
#define GEMM_BLOCKS ((N_NODES + 63) / 64)          // 313
#define CSR_BLOCKS  ((N_EDGES + 255) / 256)        // 1250
__global__ __launch_bounds__(256) void gemm_csr_kernel(const float* __restrict__ x,
                                                       const _Float16* __restrict__ wt,
                                                       unsigned char* __restrict__ h8,
                                                       const int* __restrict__ src,
                                                       const int* __restrict__ dst,
                                                       const float* __restrict__ dinv,
                                                       const int* __restrict__ offsets,
                                                       int* __restrict__ cnt2,
                                                       int2* __restrict__ csr) {
    __shared__ _Float16 bsl[16 * 16 * 32];   // 16 KB: [n-tile][col][k32]
    if (blockIdx.x >= GEMM_BLOCKS) {
        // ---------- CSR scatter ----------
        int e = (blockIdx.x - GEMM_BLOCKS) * 256 + threadIdx.x;
        if (e < N_EDGES) {
            int s = src[e], d = dst[e];
            int slot = offsets[d] + atomicAdd(&cnt2[d], 1);
            int2 pk;
            pk.x = s;
            pk.y = __float_as_int(dinv[s] * dinv[d]);
            csr[slot] = pk;
        }
        return;
    }
    // ---------- GEMM: h8 = fp8(x @ W) ----------
    const int K = IN_DIM;
    int t    = threadIdx.x;
    int wave = t >> 6;
    int lane = t & 63;
    int col  = lane & 15;
    int quad = lane >> 4;
    int row0 = blockIdx.x * 64 + wave * 16;

    f32x4 acc[16];
#pragma unroll
    for (int i = 0; i < 16; ++i) acc[i] = (f32x4){0.f, 0.f, 0.f, 0.f};

    int arow = row0 + col;
    if (arow >= N_NODES) arow = N_NODES - 1;
    const float* aptr = x + (size_t)arow * K + quad * 8;
    const uint4* wsrc = reinterpret_cast<const uint4*>(wt + (size_t)t * K); // 8 f16/uint4

    float4 pa0 = *reinterpret_cast<const float4*>(aptr);
    float4 pa1 = *reinterpret_cast<const float4*>(aptr + 4);
    uint4 b0 = wsrc[0], b1 = wsrc[1], b2 = wsrc[2], b3 = wsrc[3];

    for (int k0 = 0; k0 < K; k0 += 32) {
        __syncthreads();
        {
            uint4* d = reinterpret_cast<uint4*>(&bsl[t * 32]);
            d[0] = b0; d[1] = b1; d[2] = b2; d[3] = b3;
        }
        __syncthreads();
        half8 a;
        a[0] = (_Float16)pa0.x; a[1] = (_Float16)pa0.y;
        a[2] = (_Float16)pa0.z; a[3] = (_Float16)pa0.w;
        a[4] = (_Float16)pa1.x; a[5] = (_Float16)pa1.y;
        a[6] = (_Float16)pa1.z; a[7] = (_Float16)pa1.w;
        if (k0 + 32 < K) {
            const float* ap = aptr + k0 + 32;
            pa0 = *reinterpret_cast<const float4*>(ap);
            pa1 = *reinterpret_cast<const float4*>(ap + 4);
            const uint4* ws = wsrc + ((k0 + 32) >> 3);
            b0 = ws[0]; b1 = ws[1]; b2 = ws[2]; b3 = ws[3];
        }
#pragma unroll
        for (int nt = 0; nt < 16; ++nt) {
            half8 b = *reinterpret_cast<const half8*>(&bsl[(nt * 16 + col) * 32 + quad * 8]);
            acc[nt] = __builtin_amdgcn_mfma_f32_16x16x32_f16(a, b, acc[nt], 0, 0, 0);
        }
    }

    int orow0 = row0 + quad * 4;             // C/D: row=(lane>>4)*4+reg, col=lane&15
#pragma unroll
    for (int nt = 0; nt < 16; ++nt) {
#pragma unroll
        for (int r = 0; r < 4; ++r) {
            int rr = orow0 + r;
            if (rr < N_NODES) {
                int pk = __builtin_amdgcn_cvt_pk_fp8_f32(acc[nt][r], acc[nt][r], 0, false);
                h8[(size_t)rr * HID + nt * 16 + col] = (unsigned char)(pk & 0xff);
            }
        }
    }
}

// ---- aggregate: 4 wave-groups x 2 nodes; fp8 gathers, 4 features/thread ----
__global__ __launch_bounds__(256) void aggregate_kernel(const unsigned char* __restrict__ h8,
                                                        const float* __restrict__ bias,
                                                        const float* __restrict__ dinv,
                                                        const int* __restrict__ offsets,
                                                        const int2* __restrict__ csr,
                                                        const int* __restrict__ batch,
                                                        float* __restrict__ sums) {
    __shared__ int2 s_e[ECH];
    int v0  = blockIdx.x * NPB;
    int t   = threadIdx.x;
    int grp = t >> 6;                // wave id: 2 nodes per wave
    int fl  = t & 63;                // features 4*fl .. 4*fl+3
    int vg  = v0 + grp * 2;
    const float4 bf = *reinterpret_cast<const float4*>(bias + 4 * fl);

    int off[3];
#pragma unroll
    for (int i = 0; i <= 2; ++i) off[i] = offsets[vg + i];
    int beg0 = offsets[v0], end0 = offsets[v0 + NPB];

    float a0[2], a1[2], a2[2], a3[2];
#pragma unroll
    for (int i = 0; i < 2; ++i) {
        int v = vg + i;
        float dv = dinv[v];
        float d2 = dv * dv;
        unsigned int u = *reinterpret_cast<const unsigned int*>(h8 + (size_t)v * HID + 4 * fl);
        f32x2 lo = __builtin_amdgcn_cvt_pk_f32_fp8(u, false);
        f32x2 hi = __builtin_amdgcn_cvt_pk_f32_fp8(u, true);
        a0[i] = d2 * lo[0]; a1[i] = d2 * lo[1];
        a2[i] = d2 * hi[0]; a3[i] = d2 * hi[1];
    }

    for (int cb = beg0; cb < end0; cb += ECH) {
        int n = min(ECH, end0 - cb);
        for (int tt = t; tt < n; tt += 256) s_e[tt] = csr[cb + tt];
        __syncthreads();
#pragma unroll
        for (int i = 0; i < 2; ++i) {
            int lo_ = off[i] - cb;     if (lo_ < 0) lo_ = 0;
            int hi_ = off[i + 1] - cb; if (hi_ > n) hi_ = n;
            float x0 = a0[i], x1 = a1[i], x2 = a2[i], x3 = a3[i];
            int j = lo_;
            for (; j + 4 <= hi_; j += 4) {
                int2 e0 = s_e[j], e1 = s_e[j+1], e2 = s_e[j+2], e3 = s_e[j+3];
                unsigned int u0 = *reinterpret_cast<const unsigned int*>(h8 + (size_t)e0.x * HID + 4 * fl);
                unsigned int u1 = *reinterpret_cast<const unsigned int*>(h8 + (size_t)e1.x * HID + 4 * fl);
                unsigned int u2 = *reinterpret_cast<const unsigned int*>(h8 + (size_t)e2.x * HID + 4 * fl);
                unsigned int u3 = *reinterpret_cast<const unsigned int*>(h8 + (size_t)e3.x * HID + 4 * fl);
                float w0 = __int_as_float(e0.y), w1 = __int_as_float(e1.y);
                float w2 = __int_as_float(e2.y), w3 = __int_as_float(e3.y);
                f32x2 l0 = __builtin_amdgcn_cvt_pk_f32_fp8(u0, false);
                f32x2 h0 = __builtin_amdgcn_cvt_pk_f32_fp8(u0, true);
                f32x2 l1 = __builtin_amdgcn_cvt_pk_f32_fp8(u1, false);
                f32x2 h1 = __builtin_amdgcn_cvt_pk_f32_fp8(u1, true);
                f32x2 l2 = __builtin_amdgcn_cvt_pk_f32_fp8(u2, false);
                f32x2 h2_ = __builtin_amdgcn_cvt_pk_f32_fp8(u2, true);
                f32x2 l3 = __builtin_amdgcn_cvt_pk_f32_fp8(u3, false);
                f32x2 h3_ = __builtin_amdgcn_cvt_pk_f32_fp8(u3, true);
                x0 += w0 * l0[0] + w1 * l1[0] + w2 * l2[0] + w3 * l3[0];
                x1 += w0 * l0[1] + w1 * l1[1] + w2 * l2[1] + w3 * l3[1];
                x2 += w0 * h0[0] + w1 * h1[0] + w2 * h2_[0] + w3 * h3_[0];
                x3 += w0 * h0[1] + w1 * h1[1] + w2 * h2_[1] + w3 * h3_[1];
            }
            for (; j < hi_; ++j) {
                int2 e = s_e[j];
                unsigned int u = *reinterpret_cast<const unsigned int*>(h8 + (size_t)e.x * HID + 4 * fl);
                float w = __int_as_float(e.y);
                f32x2 lo = __builtin_amdgcn_cvt_pk_f32_fp8(u, false);
                f32x2 hi = __builtin_amdgcn_cvt_pk_f32_fp8(u, true);
                x0 += w * lo[0]; x1 += w * lo[1];
                x2 += w * hi[0]; x3 += w * hi[1];
            }
            a0[i] = x0; a1[i] = x1; a2[i] = x2; a3[i] = x3;
        }
        __syncthreads();
    }

    // relu(+bias), register pre-pool (batch sorted), flush on graph change
    float p0 = 0.f, p1 = 0.f, p2 = 0.f, p3 = 0.f;
    int cur_g = batch[vg];
#pragma unroll
    for (int i = 0; i < 2; ++i) {
        float r0 = fmaxf(a0[i] + bf.x, 0.f);
        float r1 = fmaxf(a1[i] + bf.y, 0.f);
        float r2 = fmaxf(a2[i] + bf.z, 0.f);
        float r3 = fmaxf(a3[i] + bf.w, 0.f);
        int g = batch[vg + i];
        if (g != cur_g) {
            float* sp = sums + (size_t)cur_g * HID + 4 * fl;
            atomicAdd(sp + 0, p0); atomicAdd(sp + 1, p1);
            atomicAdd(sp + 2, p2); atomicAdd(sp + 3, p3);
            p0 = p1 = p2 = p3 = 0.f;
            cur_g = g;
        }
        p0 += r0; p1 += r1; p2 += r2; p3 += r3;
    }
    float* sp = sums + (size_t)cur_g * HID + 4 * fl;
    atomicAdd(sp + 0, p0); atomicAdd(sp + 1, p1);
    atomicAdd(sp + 2, p2); atomicAdd(sp + 3, p3);
}

// ---- head: pooled = sums/count, dot lin_w, sigmoid ----
__global__ __launch_bounds__(256) void head_kernel(const float* __restrict__ sums,
                                                   const int* __restrict__ counts,
                                                   const float* __restrict__ lin_w,
                                                   const float* __restrict__ lin_b,
                                                   float* __restrict__ out) {
    int g = blockIdx.x;
    int f = threadIdx.x;
    float c = (float)counts[g];
    if (c < 1.f) c = 1.f;
    float v = (sums[(size_t)g * HID + f] / c) * lin_w[f];
#pragma unroll
    for (int off = 32; off >= 1; off >>= 1) v += __shfl_down(v, off, 64);
    __shared__ float red[4];
    if ((f & 63) == 0) red[f >> 6] = v;
    __syncthreads();
    if (f == 0) {
        float s = red[0] + red[1] + red[2] + red[3] + lin_b[0];
        out[g] = 1.0f / (1.0f + expf(-s));
    }
}

// ---------------- launch ----------------
extern "C" void kernel_launch(void* const* d_in, const int* in_sizes, int n_in,
                              void* d_out, int out_size, void* d_ws, size_t ws_size,
                              hipStream_t stream) {
    const float* x     = (const float*)d_in[0];
    const int*   edge  = (const int*)d_in[1];    // [2][E]: first E = src, next E = dst
    const int*   batch = (const int*)d_in[2];
    const float* W     = (const float*)d_in[3];
    const float* b     = (const float*)d_in[4];
    const float* lin_w = (const float*)d_in[5];
    const float* lin_b = (const float*)d_in[6];
    float*       out   = (float*)d_out;

    const int N = N_NODES, E = N_EDGES, G = N_GRAPHS, K = IN_DIM, H = HID;
    const int* src = edge;
    const int* dst = edge + E;

    char* p = (char*)d_ws;
    auto alloc = [&](size_t bytes) {
        char* r = p;
        p += (bytes + 255) & ~(size_t)255;
        return r;
    };
    _Float16*      wt      = (_Float16*)alloc((size_t)H * K * 2);
    unsigned char* h8      = (unsigned char*)alloc((size_t)N * H);
    float*         dinv    = (float*)alloc((size_t)N * 4);
    int*           offsets = (int*)alloc((size_t)(N + 1) * 4);
    int2*          csr     = (int2*)alloc((size_t)E * 8);
    // zero-region: contiguous so ONE memset covers all
    char* z0 = p;
    int*   ecnt   = (int*)alloc((size_t)N * 4);
    int*   cnt2   = (int*)alloc((size_t)N * 4);
    float* sums   = (float*)alloc((size_t)G * H * 4);
    int*   counts = (int*)alloc((size_t)G * 4);
    size_t zbytes = (size_t)(p - z0);

    hipMemsetAsync(z0, 0, zbytes, stream);

    prep_kernel<<<(PREP_B + 255) / 256, 256, 0, stream>>>(W, dst, batch, wt, ecnt, counts);
    scan_dinv_kernel<<<1, 1024, 0, stream>>>(ecnt, offsets, dinv);
    gemm_csr_kernel<<<GEMM_BLOCKS + CSR_BLOCKS, 256, 0, stream>>>(x, wt, h8, src, dst,
                                                                  dinv, offsets, cnt2, csr);
    aggregate_kernel<<<N / NPB, 256, 0, stream>>>(h8, b, dinv, offsets, csr, batch, sums);
    head_kernel<<<G, 256, 0, stream>>>(sums, counts, lin_w, lin_b, out);
}

// Round 5
// 185.120 us; speedup vs baseline: 1.1640x; 1.1640x over previous
//
#include <hip/hip_runtime.h>
#include <hip/hip_bf16.h>
#include <cstdint>

typedef __attribute__((ext_vector_type(8))) _Float16 half8;
typedef __attribute__((ext_vector_type(2))) float f32x2;
typedef __attribute__((ext_vector_type(4))) float f32x4;

#define N_NODES 20000
#define N_EDGES 320000
#define IN_DIM 512
#define HID 256
#define N_GRAPHS 256
#define NPB 8            // nodes per aggregate block (4 waves x 2 nodes)
#define ECH 1024         // edge-staging chunk (int2 -> 8 KB LDS, unioned w/ pool)

// ---- prep: W transpose->f16  +  in-degree hist over dst  +  batch hist ----
#define PREP_W   (IN_DIM * HID)            // 131072
#define PREP_E   (PREP_W + N_EDGES)        // 451072
#define PREP_B   (PREP_E + N_NODES)        // 471072
__global__ __launch_bounds__(256) void prep_kernel(const float* __restrict__ W,
                                                   const int* __restrict__ dst,
                                                   const int* __restrict__ batch,
                                                   _Float16* __restrict__ wt,
                                                   int* __restrict__ ecnt,
                                                   int* __restrict__ counts) {
    int t = blockIdx.x * 256 + threadIdx.x;
    if (t < PREP_W) {
        wt[t] = (_Float16)W[(t & 511) * HID + (t >> 9)];   // wt[n*512+k] = W[k*256+n]
    } else if (t < PREP_E) {
        atomicAdd(&ecnt[dst[t - PREP_W]], 1);
    } else if (t < PREP_B) {
        atomicAdd(&counts[batch[t - PREP_E]], 1);
    }
}

// ---- single-block scan of ecnt -> offsets[0..N], fused dinv; shfl wave-scans ----
__global__ __launch_bounds__(1024) void scan_dinv_kernel(const int* __restrict__ ecnt,
                                                         int* __restrict__ offsets,
                                                         float* __restrict__ dinv) {
    __shared__ int wsum[16];
    int t = threadIdx.x;
    int lane = t & 63, wid = t >> 6;
    const int CHS = 20;                    // 1024*20 >= 20000; t<1000 fully in-range
    int base = t * CHS;
    int vals[CHS];
    int s = 0;
    if (t < 1000) {
        const int4* p = reinterpret_cast<const int4*>(ecnt + base);
#pragma unroll
        for (int i = 0; i < 5; ++i) {
            int4 v = p[i];
            vals[4*i+0] = v.x; vals[4*i+1] = v.y; vals[4*i+2] = v.z; vals[4*i+3] = v.w;
        }
#pragma unroll
        for (int i = 0; i < CHS; ++i) s += vals[i];
    }
    int incl = s;
#pragma unroll
    for (int off = 1; off < 64; off <<= 1) {
        int u = __shfl_up(incl, off, 64);
        if (lane >= off) incl += u;
    }
    if (lane == 63) wsum[wid] = incl;
    __syncthreads();
    if (t < 16) {
        int v = wsum[t];
#pragma unroll
        for (int off = 1; off < 16; off <<= 1) {
            int u = __shfl_up(v, off, 16);
            if (t >= off) v += u;
        }
        wsum[t] = v;
    }
    __syncthreads();
    int woff = (wid == 0) ? 0 : wsum[wid - 1];
    if (t < 1000) {
        int run = woff + incl - s;
#pragma unroll
        for (int i = 0; i < CHS; ++i) {
            int idx = base + i;
            offsets[idx] = run;
            dinv[idx] = rsqrtf((float)(vals[i] + 1));
            run += vals[i];
        }
    }
    if (t == 1023) offsets[N_NODES] = wsum[15];
}

// ---- fused: gemm (blocks [0,GEMM_BLOCKS)) + csr scatter (rest) ----
#define GEMM_BLOCKS ((N_NODES + 63) / 64)          // 313
#define CSR_BLOCKS  ((N_EDGES + 255) / 256)        // 1250
__global__ __launch_bounds__(256) void gemm_csr_kernel(const float* __restrict__ x,
                                                       const _Float16* __restrict__ wt,
                                                       unsigned char* __restrict__ h8,
                                                       const int* __restrict__ src,
                                                       const int* __restrict__ dst,
                                                       const float* __restrict__ dinv,
                                                       const int* __restrict__ offsets,
                                                       int* __restrict__ cnt2,
                                                       int2* __restrict__ csr) {
    __shared__ _Float16 bsl[16 * 16 * 32];   // 16 KB: [n-tile][col][k32]
    if (blockIdx.x >= GEMM_BLOCKS) {
        int e = (blockIdx.x - GEMM_BLOCKS) * 256 + threadIdx.x;
        if (e < N_EDGES) {
            int s = src[e], d = dst[e];
            int slot = offsets[d] + atomicAdd(&cnt2[d], 1);
            int2 pk;
            pk.x = s;
            pk.y = __float_as_int(dinv[s] * dinv[d]);
            csr[slot] = pk;
        }
        return;
    }
    // ---------- GEMM: h8 = fp8(x @ W) ----------
    const int K = IN_DIM;
    int t    = threadIdx.x;
    int wave = t >> 6;
    int lane = t & 63;
    int col  = lane & 15;
    int quad = lane >> 4;
    int row0 = blockIdx.x * 64 + wave * 16;

    f32x4 acc[16];
#pragma unroll
    for (int i = 0; i < 16; ++i) acc[i] = (f32x4){0.f, 0.f, 0.f, 0.f};

    int arow = row0 + col;
    if (arow >= N_NODES) arow = N_NODES - 1;
    const float* aptr = x + (size_t)arow * K + quad * 8;
    const uint4* wsrc = reinterpret_cast<const uint4*>(wt + (size_t)t * K); // 8 f16/uint4

    float4 pa0 = *reinterpret_cast<const float4*>(aptr);
    float4 pa1 = *reinterpret_cast<const float4*>(aptr + 4);
    uint4 b0 = wsrc[0], b1 = wsrc[1], b2 = wsrc[2], b3 = wsrc[3];

    for (int k0 = 0; k0 < K; k0 += 32) {
        __syncthreads();
        {
            uint4* d = reinterpret_cast<uint4*>(&bsl[t * 32]);
            d[0] = b0; d[1] = b1; d[2] = b2; d[3] = b3;
        }
        __syncthreads();
        half8 a;
        a[0] = (_Float16)pa0.x; a[1] = (_Float16)pa0.y;
        a[2] = (_Float16)pa0.z; a[3] = (_Float16)pa0.w;
        a[4] = (_Float16)pa1.x; a[5] = (_Float16)pa1.y;
        a[6] = (_Float16)pa1.z; a[7] = (_Float16)pa1.w;
        if (k0 + 32 < K) {
            const float* ap = aptr + k0 + 32;
            pa0 = *reinterpret_cast<const float4*>(ap);
            pa1 = *reinterpret_cast<const float4*>(ap + 4);
            const uint4* ws = wsrc + ((k0 + 32) >> 3);
            b0 = ws[0]; b1 = ws[1]; b2 = ws[2]; b3 = ws[3];
        }
#pragma unroll
        for (int nt = 0; nt < 16; ++nt) {
            half8 b = *reinterpret_cast<const half8*>(&bsl[(nt * 16 + col) * 32 + quad * 8]);
            acc[nt] = __builtin_amdgcn_mfma_f32_16x16x32_f16(a, b, acc[nt], 0, 0, 0);
        }
    }

    int orow0 = row0 + quad * 4;             // C/D: row=(lane>>4)*4+reg, col=lane&15
#pragma unroll
    for (int nt = 0; nt < 16; ++nt) {
#pragma unroll
        for (int r = 0; r < 4; ++r) {
            int rr = orow0 + r;
            if (rr < N_NODES) {
                int pk = __builtin_amdgcn_cvt_pk_fp8_f32(acc[nt][r], acc[nt][r], 0, false);
                h8[(size_t)rr * HID + nt * 16 + col] = (unsigned char)(pk & 0xff);
            }
        }
    }
}

// ---- aggregate: 4 waves x 2 nodes; fp8 gathers; LDS-transposed coalesced pool ----
__global__ __launch_bounds__(256, 8) void aggregate_kernel(const unsigned char* __restrict__ h8,
                                                           const float* __restrict__ bias,
                                                           const float* __restrict__ dinv,
                                                           const int* __restrict__ offsets,
                                                           const int2* __restrict__ csr,
                                                           const int* __restrict__ batch,
                                                           float* __restrict__ sums) {
    __shared__ int2 s_e[ECH];                               // 8 KB
    float* pool = reinterpret_cast<float*>(s_e);            // union: [8][256] f32
    int v0  = blockIdx.x * NPB;
    int t   = threadIdx.x;
    int grp = t >> 6;                // wave id: 2 nodes per wave
    int fl  = t & 63;                // features 4*fl .. 4*fl+3
    int vg  = v0 + grp * 2;
    const float4 bf = *reinterpret_cast<const float4*>(bias + 4 * fl);

    int off[3];
#pragma unroll
    for (int i = 0; i <= 2; ++i) off[i] = offsets[vg + i];
    int beg0 = offsets[v0], end0 = offsets[v0 + NPB];

    float a0[2], a1[2], a2[2], a3[2];
#pragma unroll
    for (int i = 0; i < 2; ++i) {
        int v = vg + i;
        float dv = dinv[v];
        float d2 = dv * dv;
        unsigned int u = *reinterpret_cast<const unsigned int*>(h8 + (size_t)v * HID + 4 * fl);
        f32x2 lo = __builtin_amdgcn_cvt_pk_f32_fp8(u, false);
        f32x2 hi = __builtin_amdgcn_cvt_pk_f32_fp8(u, true);
        a0[i] = d2 * lo[0]; a1[i] = d2 * lo[1];
        a2[i] = d2 * hi[0]; a3[i] = d2 * hi[1];
    }

    for (int cb = beg0; cb < end0; cb += ECH) {
        int n = min(ECH, end0 - cb);
        for (int tt = t; tt < n; tt += 256) s_e[tt] = csr[cb + tt];
        __syncthreads();
#pragma unroll
        for (int i = 0; i < 2; ++i) {
            int lo_ = off[i] - cb;     if (lo_ < 0) lo_ = 0;
            int hi_ = off[i + 1] - cb; if (hi_ > n) hi_ = n;
            float x0 = a0[i], x1 = a1[i], x2 = a2[i], x3 = a3[i];
            int j = lo_;
            for (; j + 8 <= hi_; j += 8) {
#pragma unroll
                for (int q = 0; q < 8; ++q) {
                    int2 e = s_e[j + q];
                    unsigned int u = *reinterpret_cast<const unsigned int*>(
                        h8 + (size_t)e.x * HID + 4 * fl);
                    float w = __int_as_float(e.y);
                    f32x2 lo = __builtin_amdgcn_cvt_pk_f32_fp8(u, false);
                    f32x2 hi = __builtin_amdgcn_cvt_pk_f32_fp8(u, true);
                    x0 += w * lo[0]; x1 += w * lo[1];
                    x2 += w * hi[0]; x3 += w * hi[1];
                }
            }
            for (; j < hi_; ++j) {
                int2 e = s_e[j];
                unsigned int u = *reinterpret_cast<const unsigned int*>(
                    h8 + (size_t)e.x * HID + 4 * fl);
                float w = __int_as_float(e.y);
                f32x2 lo = __builtin_amdgcn_cvt_pk_f32_fp8(u, false);
                f32x2 hi = __builtin_amdgcn_cvt_pk_f32_fp8(u, true);
                x0 += w * lo[0]; x1 += w * lo[1];
                x2 += w * hi[0]; x3 += w * hi[1];
            }
            a0[i] = x0; a1[i] = x1; a2[i] = x2; a3[i] = x3;
        }
        __syncthreads();
    }

    // relu(+bias) -> LDS pool[node][feature] (edge loop's trailing barrier, or
    // zero-edge case where s_e was never read, makes this safe)
#pragma unroll
    for (int i = 0; i < 2; ++i) {
        f32x4 r;
        r[0] = fmaxf(a0[i] + bf.x, 0.f);
        r[1] = fmaxf(a1[i] + bf.y, 0.f);
        r[2] = fmaxf(a2[i] + bf.z, 0.f);
        r[3] = fmaxf(a3[i] + bf.w, 0.f);
        *reinterpret_cast<f32x4*>(&pool[(grp * 2 + i) * HID + 4 * fl]) = r;
    }
    __syncthreads();

    // coalesced flush: thread = feature, one atomic per graph-segment
    float acc = 0.f;
    int cur_g = batch[v0];
#pragma unroll
    for (int i = 0; i < NPB; ++i) {
        float val = pool[i * HID + t];
        int g = batch[v0 + i];
        if (g != cur_g) {
            atomicAdd(&sums[(size_t)cur_g * HID + t], acc);
            acc = 0.f;
            cur_g = g;
        }
        acc += val;
    }
    atomicAdd(&sums[(size_t)cur_g * HID + t], acc);
}

// ---- head: pooled = sums/count, dot lin_w, sigmoid ----
__global__ __launch_bounds__(256) void head_kernel(const float* __restrict__ sums,
                                                   const int* __restrict__ counts,
                                                   const float* __restrict__ lin_w,
                                                   const float* __restrict__ lin_b,
                                                   float* __restrict__ out) {
    int g = blockIdx.x;
    int f = threadIdx.x;
    float c = (float)counts[g];
    if (c < 1.f) c = 1.f;
    float v = (sums[(size_t)g * HID + f] / c) * lin_w[f];
#pragma unroll
    for (int off = 32; off >= 1; off >>= 1) v += __shfl_down(v, off, 64);
    __shared__ float red[4];
    if ((f & 63) == 0) red[f >> 6] = v;
    __syncthreads();
    if (f == 0) {
        float s = red[0] + red[1] + red[2] + red[3] + lin_b[0];
        out[g] = 1.0f / (1.0f + expf(-s));
    }
}

// ---------------- launch ----------------
extern "C" void kernel_launch(void* const* d_in, const int* in_sizes, int n_in,
                              void* d_out, int out_size, void* d_ws, size_t ws_size,
                              hipStream_t stream) {
    const float* x     = (const float*)d_in[0];
    const int*   edge  = (const int*)d_in[1];    // [2][E]: first E = src, next E = dst
    const int*   batch = (const int*)d_in[2];
    const float* W     = (const float*)d_in[3];
    const float* b     = (const float*)d_in[4];
    const float* lin_w = (const float*)d_in[5];
    const float* lin_b = (const float*)d_in[6];
    float*       out   = (float*)d_out;

    const int N = N_NODES, E = N_EDGES, G = N_GRAPHS, K = IN_DIM, H = HID;
    const int* src = edge;
    const int* dst = edge + E;

    char* p = (char*)d_ws;
    auto alloc = [&](size_t bytes) {
        char* r = p;
        p += (bytes + 255) & ~(size_t)255;
        return r;
    };
    _Float16*      wt      = (_Float16*)alloc((size_t)H * K * 2);
    unsigned char* h8      = (unsigned char*)alloc((size_t)N * H);
    float*         dinv    = (float*)alloc((size_t)N * 4);
    int*           offsets = (int*)alloc((size_t)(N + 1) * 4);
    int2*          csr     = (int2*)alloc((size_t)E * 8);
    // zero-region: contiguous so ONE memset covers all
    char* z0 = p;
    int*   ecnt   = (int*)alloc((size_t)N * 4);
    int*   cnt2   = (int*)alloc((size_t)N * 4);
    float* sums   = (float*)alloc((size_t)G * H * 4);
    int*   counts = (int*)alloc((size_t)G * 4);
    size_t zbytes = (size_t)(p - z0);

    hipMemsetAsync(z0, 0, zbytes, stream);

    prep_kernel<<<(PREP_B + 255) / 256, 256, 0, stream>>>(W, dst, batch, wt, ecnt, counts);
    scan_dinv_kernel<<<1, 1024, 0, stream>>>(ecnt, offsets, dinv);
    gemm_csr_kernel<<<GEMM_BLOCKS + CSR_BLOCKS, 256, 0, stream>>>(x, wt, h8, src, dst,
                                                                  dinv, offsets, cnt2, csr);
    aggregate_kernel<<<N / NPB, 256, 0, stream>>>(h8, b, dinv, offsets, csr, batch, sums);
    head_kernel<<<G, 256, 0, stream>>>(sums, counts, lin_w, lin_b, out);
}